// Round 15
// baseline (1824.877 us; speedup 1.0000x reference)
//
#include <hip/hip_runtime.h>
#include <math.h>

// Problem constants
#define NN 4096
#define TT 48
#define HH 64
#define GG 256   // 4*H
#define PP 12
#define CAP 192  // ELL slots per row, 3 x 64 -> whole-wave chunk loads, no guard
#define NH (NN * HH)

// readlane broadcast: uniform lane index -> SGPR broadcast, off the LDS pipe
__device__ __forceinline__ float bcast_f(float v, int lane) {
  return __int_as_float(__builtin_amdgcn_readlane(__float_as_int(v), lane));
}
__device__ __forceinline__ int bcast_i(int v, int lane) {
  return __builtin_amdgcn_readlane(v, lane);
}

// fp32 -> bf16 (round-to-nearest-even), packed pairs; unpack is 1 VALU op
// per value (bf16 = fp32 high half).
__device__ __forceinline__ unsigned int f2bf(float f) {
  unsigned int u = __float_as_uint(f);
  u += 0x7fffu + ((u >> 16) & 1u);
  return u >> 16;
}
__device__ __forceinline__ uint2 packq(float a, float b, float c, float d) {
  uint2 r;
  r.x = f2bf(a) | (f2bf(b) << 16);
  r.y = f2bf(c) | (f2bf(d) << 16);
  return r;
}
__device__ __forceinline__ float4 unpackq(uint2 u) {
  return make_float4(__uint_as_float(u.x << 16),
                     __uint_as_float(u.x & 0xffff0000u),
                     __uint_as_float(u.y << 16),
                     __uint_as_float(u.y & 0xffff0000u));
}

// ---------------------------------------------------------------------------
// h-state: paired buffers P[2], each [N][64][2]: {h0, h1} interleaved.
// Launch k (k=0..48) computes cell0(t=k) [k<48] and cell1(s=k-1) [k>0]:
//   READS only P[(k&1)^1], WRITES only P[k&1] (disjoint float2 slots).
// Final h1(47) in P[0].y.
//
// R14 = R13 resubmitted (R13's bench was a broker-infra failure, same
// signature as R1 which passed verbatim on retry; kernel re-audited: all
// barriers block-uniform, LDS indexing in-bounds, prefetch chain covers
// uint4 [0,12288) exactly, no data-dependent loops).
//
// R13 = R12 (verified 1736us) + BF16-PACKED WEIGHTS in global+LDS.
// Diagnosis: per-step ~33us decomposes as VALU ~12us (VALUBusy 37% x 33)
// and LDS pipe ~19us (16 waves/CU x 192 ds_read_b128 @ ~12cy + staging
// writes) -- LDS is the near-critical resource (~58%), which explains both
// R10's TLP win (better overlap of the same LDS stream) and R8's null
// (barriers weren't the stall). Lever: halve LDS bytes. Weights prepacked
// bf16 (RNE) in k_prep; dense loops ds_read_b64 per gate-quad + 1-op/value
// unpack; ga/hl/acc/epilogues stay fp32 (only W rounded). Structure,
// barriers, k-split, slot indexing identical to R12. PRE-COMMITTED reads:
// absmax > 3e-3 -> revert R12 + declare floor; pass + dur drop -> LDS
// theory confirmed.
// History: R0 48.5 -> R6 42.4 (unroll-1 ping-pong; R4/R5: constant-trip
// ch-loops MUST be #pragma unroll 1) -> R7 40.0 (merged roles) -> R9 48
// (1 wave/SIMD fails) -> R10 ~33us/launch 1727 total -> R11 cooperative
// FAILED (not capturable + cross-XCD coherence) -> R12 1736 (consolidated).
//
// GATE-QUAD mapping: lane j owns cols {j, j+64, j+128, j+192} = (i,f,o,g)
// of hidden unit j, packed as one uint2 (4 x bf16). PERMUTED slot order
// (chunk-interleaved k-halves), same as R10/R12:
//   Wg0: slot0(k) = (k%32/4)*8 + (k/32)*4 + (k%4);  u2 = slot*128 + m*64 + j
//        m in {gcWh0, liWh0}; chunk c (8 slots) holds k {4c..4c+3, 32+4c..}
//   Wg1: slot1(k) = (k%32/2)*4 + (k/32)*2 + (k%2);  u2 = 8192 + slot*256
//        + m*64 + j; m in {gcWi1, liWi1, gcWh1, liWh1}; chunk c (4 slots)
//        holds k {2c, 2c+1, 32+2c, 32+2c+1}
// Chunk = 1024 uint2 = 8 KB = 512 uint4 -> 1 uint4 global load + 1
// ds_write_b128 per thread per chunk.
// ---------------------------------------------------------------------------
__launch_bounds__(256)
__global__ void k_prep(const float* gcbi0, const float* gcbh0,
                       const float* libi0, const float* libh0,
                       const float* gcbi1, const float* gcbh1,
                       const float* libi1, const float* libh1,
                       const float* gcWh0, const float* liWh0,
                       const float* gcWi1, const float* liWi1,
                       const float* gcWh1, const float* liWh1,
                       const float* gcWi0, const float* liWi0,
                       float* state, uint2* Wg0, uint2* Wg1,
                       float4* biasg0, float4* biasg1, float4* xq0) {
  int idx = blockIdx.x * 256 + threadIdx.x;
  int stride = gridDim.x * 256;
  for (int i = idx; i < 6 * NH; i += stride) state[i] = 0.0f;  // P0,P1,c0,c1
  for (int i = idx; i < 64 * 2 * 64; i += stride) {
    int j = i & 63, m = (i >> 6) & 1, k = i >> 7;
    const float* W = m ? liWh0 : gcWh0;
    int slot = ((k & 31) >> 2) * 8 + (k >> 5) * 4 + (k & 3);
    Wg0[slot * 128 + m * 64 + j] =
        packq(W[k * GG + j], W[k * GG + j + 64],
              W[k * GG + j + 128], W[k * GG + j + 192]);
  }
  for (int i = idx; i < 64 * 4 * 64; i += stride) {
    int j = i & 63, m = (i >> 6) & 3, k = i >> 8;
    const float* W = (m == 0) ? gcWi1 : (m == 1) ? liWi1 : (m == 2) ? gcWh1 : liWh1;
    int slot = ((k & 31) >> 1) * 4 + (k >> 5) * 2 + (k & 1);
    Wg1[slot * 256 + m * 64 + j] =
        packq(W[k * GG + j], W[k * GG + j + 64],
              W[k * GG + j + 128], W[k * GG + j + 192]);
  }
  if (idx < 64) {
    int j = idx;
    biasg0[j] = make_float4(
        gcbi0[j] + gcbh0[j] + libi0[j] + libh0[j],
        gcbi0[j + 64] + gcbh0[j + 64] + libi0[j + 64] + libh0[j + 64],
        gcbi0[j + 128] + gcbh0[j + 128] + libi0[j + 128] + libh0[j + 128],
        gcbi0[j + 192] + gcbh0[j + 192] + libi0[j + 192] + libh0[j + 192]);
    biasg1[j] = make_float4(
        gcbi1[j] + gcbh1[j] + libi1[j] + libh1[j],
        gcbi1[j + 64] + gcbh1[j + 64] + libi1[j + 64] + libh1[j + 64],
        gcbi1[j + 128] + gcbh1[j + 128] + libi1[j + 128] + libh1[j + 128],
        gcbi1[j + 192] + gcbh1[j + 192] + libi1[j + 192] + libh1[j + 192]);
  } else if (idx < 320) {
    int i = idx - 64;           // i = m*64 + j
    int j = i & 63, m = i >> 6; // m: 0,1 -> gcWi0 row 0/1; 2,3 -> liWi0 row 0/1
    const float* W = (m < 2) ? gcWi0 : liWi0;
    int kk = m & 1;
    xq0[i] = make_float4(W[kk * GG + j], W[kk * GG + j + 64],
                         W[kk * GG + j + 128], W[kk * GG + j + 192]);
  }
}

// ---------------------------------------------------------------------------
// Single adj pass: raw ELL (incl. +I diag) + dinv. Zero-fills ALL CAP slots
// (re-poison semantics: padding must be (col=0, val=0)). cnt padded to x8.
// ---------------------------------------------------------------------------
__launch_bounds__(256)
__global__ void k_build(const float* adj, float* dinv,
                        int* ell_col, float* ell_val, int* ell_cnt) {
  int r = blockIdx.x;
  __shared__ int cnt;
  __shared__ float red[256];
  if (threadIdx.x == 0) cnt = 0;
  __syncthreads();
  const float* row = adj + (size_t)r * NN;
  float s = 0.0f;
  for (int c = threadIdx.x; c < NN; c += 256) {
    float a = row[c];
    if (c == r) a += 1.0f;   // A = adj + I
    s += a;
    if (a != 0.0f) {
      int pos = atomicAdd(&cnt, 1);
      if (pos < CAP) {
        ell_col[(size_t)r * CAP + pos] = c;
        ell_val[(size_t)r * CAP + pos] = a;
      }
    }
  }
  red[threadIdx.x] = s;
  __syncthreads();
  for (int st = 128; st > 0; st >>= 1) {
    if (threadIdx.x < st) red[threadIdx.x] += red[threadIdx.x + st];
    __syncthreads();
  }
  int n = cnt < CAP ? cnt : CAP;
  for (int j = n + (int)threadIdx.x; j < CAP; j += 256) {
    ell_col[(size_t)r * CAP + j] = 0;
    ell_val[(size_t)r * CAP + j] = 0.0f;
  }
  if (threadIdx.x == 0) {
    int npad = (n + 7) & ~7;
    if (npad > CAP) npad = CAP;
    ell_cnt[r] = npad;
    dinv[r] = 1.0f / sqrtf(red[0]);  // rowsum + 1 >= 1
  }
}

__launch_bounds__(256)
__global__ void k_scale(const float* dinv, const int* ell_col, float* ell_val) {
  int idx = blockIdx.x * 256 + threadIdx.x;  // over NN*CAP
  int r = idx / CAP;
  if (r >= NN) return;
  float v = ell_val[idx];
  if (v != 0.0f) ell_val[idx] = v * dinv[r] * dinv[ell_col[idx]];
}

// ---------------------------------------------------------------------------
// Precompute gax[t][r][c] = (A @ x_t)[r][c]. Block = (t, 512-row segment).
// ---------------------------------------------------------------------------
__launch_bounds__(256)
__global__ void k_gax(const float* x, const int* ell_col, const float* ell_val,
                      const int* ell_cnt, float* gax) {
  int t = blockIdx.x >> 3;
  int seg = blockIdx.x & 7;
  __shared__ float xs[NN * 2];
  const float* xt = x + (size_t)t * NN * 2;
  for (int i = threadIdx.x; i < NN * 2; i += 256) xs[i] = xt[i];
  __syncthreads();
  int base = seg * 512 * 2;
  for (int oo = threadIdx.x; oo < 512 * 2; oo += 256) {
    int o = base + oo;
    int r = o >> 1, cmp = o & 1;
    int cnt = ell_cnt[r];
    const int* cp = ell_col + (size_t)r * CAP;
    const float* vp = ell_val + (size_t)r * CAP;
    float acc = 0.0f;
    for (int j = 0; j < cnt; j += 4) {
      acc += vp[j]     * xs[cp[j]     * 2 + cmp];
      acc += vp[j + 1] * xs[cp[j + 1] * 2 + cmp];
      acc += vp[j + 2] * xs[cp[j + 2] * 2 + cmp];
      acc += vp[j + 3] * xs[cp[j + 3] * 2 + cmp];
    }
    gax[(size_t)t * NN * 2 + o] = acc;
  }
}

// ---------------------------------------------------------------------------
// Merged k-split step kernel: 512 threads = 8 waves = 4 pairs x 2 k-halves.
// 8 rows/block (2 per pair). Wave (pair,kh) gathers row r0+kh; pair
// exchanges ga via xbuf; both dense loops computed per k-half on every
// chunk (interleaved layout). kh=0 finalizes cell0, kh=1 cell1.
// Weights bf16-packed: chunk = 8 KB; ds_read_b64 per quad + unpack.
// LDS: 2 x 8 KB ping-pong + 8 KB exchange/reduction = 24 KB.
// ---------------------------------------------------------------------------
__launch_bounds__(512, 4)
__global__ void k_cells(int c0on, int c1on,
                        const int* __restrict__ ell_col,
                        const float* __restrict__ ell_val,
                        const int* __restrict__ ell_cnt,
                        const float2* __restrict__ Pr, float* __restrict__ Pw,
                        float* __restrict__ c0, float* __restrict__ c1,
                        const float* __restrict__ xt, const float* __restrict__ gaxt,
                        const uint2* __restrict__ Wg,
                        const float4* __restrict__ biasg0,
                        const float4* __restrict__ xq0,
                        const float4* __restrict__ biasg1) {
  __shared__ uint4 wbuf4[1024];  // 2 x 8 KB ping-pong (1024 uint2 per half)
  __shared__ float4 xbuf[512];   // 8 KB: ga-exchange (early), acc-reduce (late)
  const int tid = threadIdx.x;
  const int wave = tid >> 6, lane = tid & 63;
  const int pair = wave >> 1, kh = wave & 1;
  const int r0 = blockIdx.x * 8 + pair * 2;
  const int myrow = r0 + kh;

  // chunk-0 prefetch (1 uint4/thread = 2 quads): completes under the gather.
  // When loop A is disabled (k==TT launch), chain starts at Wg1 (uint4 4096).
  const uint4* pf = ((const uint4*)Wg) + (c0on ? 0 : 4096) + tid;
  uint4 st = pf[0];
  pf += 512;

  // c-state loads for the role this wave finalizes (kh=0: cell0, kh=1: cell1)
  float cprevA[2];
#pragma unroll
  for (int rr = 0; rr < 2; rr++) {
    size_t gi = (size_t)(r0 + rr) * HH + lane;
    cprevA[rr] = (kh == 0) ? c0[gi] : c1[gi];
  }

  // gather OWN row (both float2 components)
  int cnt = ell_cnt[myrow];
  int myc[3]; float myv[3];
#pragma unroll
  for (int chk = 0; chk < 3; chk++) {
    myc[chk] = ell_col[(size_t)myrow * CAP + chk * 64 + lane];
    myv[chk] = ell_val[(size_t)myrow * CAP + chk * 64 + lane];
  }
  float a0 = 0.0f, a1 = 0.0f;
#pragma unroll
  for (int chk = 0; chk < 3; chk++) {
    int base = chk * 64;
    if (base < cnt) {
      int lim = cnt - base; if (lim > 64) lim = 64;  // multiple of 8
      int mc = myc[chk]; float mv = myv[chk];
      for (int m = 0; m < lim; m += 8) {
        float2 ld[8]; float vv[8];
#pragma unroll
        for (int i = 0; i < 8; i++) {
          int cc = bcast_i(mc, m + i);
          vv[i] = bcast_f(mv, m + i);
          ld[i] = Pr[(size_t)cc * 64 + lane];
        }
#pragma unroll
        for (int i = 0; i < 8; i++) {
          a0 += vv[i] * ld[i].x;
          a1 += vv[i] * ld[i].y;
        }
      }
    }
  }
  // publish ga for my row; load hl for both rows directly
  {
    float2* gx = (float2*)xbuf;
    gx[(size_t)(pair * 2 + kh) * 64 + lane] = make_float2(a0, a1);
  }
  float hl0[2], hl1[2];
#pragma unroll
  for (int rr = 0; rr < 2; rr++) {
    float2 hh = Pr[(size_t)(r0 + rr) * 64 + lane];
    hl0[rr] = hh.x;  // h0(k-1): cell0 liWh0 + cell1 liWi1
    hl1[rr] = hh.y;  // h1(k-2): cell1 liWh1
  }

  // accumulator inits: bias/x terms live in exactly one k-half
  float4 acc0[2], acc1[2];
  if (kh == 0) {
    float4 b = biasg0[lane];
    float4 qg0 = xq0[lane], qg1 = xq0[64 + lane];
    float4 ql0 = xq0[128 + lane], ql1 = xq0[192 + lane];
#pragma unroll
    for (int rr = 0; rr < 2; rr++) {
      float xx0 = xt[(size_t)(r0 + rr) * 2];
      float xx1 = xt[(size_t)(r0 + rr) * 2 + 1];
      float gg0 = gaxt[(size_t)(r0 + rr) * 2];
      float gg1 = gaxt[(size_t)(r0 + rr) * 2 + 1];
      acc0[rr].x = b.x + gg0 * qg0.x + gg1 * qg1.x + xx0 * ql0.x + xx1 * ql1.x;
      acc0[rr].y = b.y + gg0 * qg0.y + gg1 * qg1.y + xx0 * ql0.y + xx1 * ql1.y;
      acc0[rr].z = b.z + gg0 * qg0.z + gg1 * qg1.z + xx0 * ql0.z + xx1 * ql1.z;
      acc0[rr].w = b.w + gg0 * qg0.w + gg1 * qg1.w + xx0 * ql0.w + xx1 * ql1.w;
    }
    acc1[0] = make_float4(0.f, 0.f, 0.f, 0.f);
    acc1[1] = make_float4(0.f, 0.f, 0.f, 0.f);
  } else {
    acc0[0] = make_float4(0.f, 0.f, 0.f, 0.f);
    acc0[1] = make_float4(0.f, 0.f, 0.f, 0.f);
    float4 b1 = biasg1[lane];
    acc1[0] = b1; acc1[1] = b1;
  }

  // stage chunk 0; barrier makes gx + chunk0 visible
  wbuf4[tid] = st;
  __syncthreads();

  // read pair's ga for both rows
  float ga0[2], ga1[2];
  {
    const float2* gx = (const float2*)xbuf;
#pragma unroll
    for (int rr = 0; rr < 2; rr++) {
      float2 g = gx[(size_t)(pair * 2 + rr) * 64 + lane];
      ga0[rr] = g.x;  // A@h0(k-1): cell0 gcWh0 + cell1 gcWi1
      ga1[rr] = g.y;  // A@h1(k-2): cell1 gcWh1
    }
  }

  int cur = 0;
  if (c0on) {
    // loop A: Wg0, 8 chunks; each wave computes its 4 k's per chunk.
    // ALWAYS prefetch next (ch=7 pulls Wg1 chunk 0 across the boundary).
#pragma unroll 1
    for (int ch = 0; ch < 8; ch++) {
      st = pf[0];
      pf += 512;
      const uint2* wb = ((const uint2*)wbuf4) + (cur << 10);
      const int kb = kh * 32 + ch * 4;
      const int wbase = kh * 4;
#pragma unroll
      for (int q = 0; q < 4; q++) {
        int k = kb + q;
        float4 w0 = unpackq(wb[(wbase + q) * 128 + lane]);
        float4 w1 = unpackq(wb[(wbase + q) * 128 + 64 + lane]);
#pragma unroll
        for (int rr = 0; rr < 2; rr++) {
          float b0 = bcast_f(ga0[rr], k);
          float b1 = bcast_f(hl0[rr], k);
          acc0[rr].x += b0 * w0.x + b1 * w1.x;
          acc0[rr].y += b0 * w0.y + b1 * w1.y;
          acc0[rr].z += b0 * w0.z + b1 * w1.z;
          acc0[rr].w += b0 * w0.w + b1 * w1.w;
        }
      }
      cur ^= 1;
      wbuf4[(cur << 9) + tid] = st;
      if (ch == 7 && kh == 1) {  // stash acc0 partials before the barrier
        xbuf[(size_t)(pair * 2 + 0) * 64 + lane] = acc0[0];
        xbuf[(size_t)(pair * 2 + 1) * 64 + lane] = acc0[1];
      }
      __syncthreads();  // writes + stash visible; all waves past chunk ch
    }

    // cell0 reduce + epilogue (kh=0); overlaps kh=1's loop-B start
    if (kh == 0) {
#pragma unroll
      for (int rr = 0; rr < 2; rr++) {
        float4 o = xbuf[(size_t)(pair * 2 + rr) * 64 + lane];
        float gxv = acc0[rr].x + o.x, gyv = acc0[rr].y + o.y;
        float gzv = acc0[rr].z + o.z, gwv = acc0[rr].w + o.w;
        size_t gi = (size_t)(r0 + rr) * HH + lane;
        float si = 1.0f / (1.0f + __expf(-gxv));
        float sf = 1.0f / (1.0f + __expf(-gyv));
        float so = 1.0f / (1.0f + __expf(-gzv));
        float cn = sf * cprevA[rr] + si * tanhf(gwv);
        float hn = so * tanhf(cn);
        c0[gi] = cn;
        Pw[gi * 2 + 0] = hn;
      }
    }
  }

  if (c1on) {
    // loop B: Wg1, 16 chunks; each wave computes its 2 k's per chunk.
    // buf[cur] holds Wg1 chunk 0 (staged at ch=7 above, or at entry when
    // loop A was skipped).
#pragma unroll 1
    for (int ch = 0; ch < 16; ch++) {
      if (ch + 1 < 16) {
        st = pf[0];
        pf += 512;
      }
      const uint2* wb = ((const uint2*)wbuf4) + (cur << 10);
      const int kb = kh * 32 + ch * 2;
      const int wbase = kh * 2;
#pragma unroll
      for (int q = 0; q < 2; q++) {
        int k = kb + q;
        const uint2* wp = wb + (wbase + q) * 256 + lane;
        float4 w0 = unpackq(wp[0]);
        float4 w1 = unpackq(wp[64]);
        float4 w2 = unpackq(wp[128]);
        float4 w3 = unpackq(wp[192]);
#pragma unroll
        for (int rr = 0; rr < 2; rr++) {
          float b0 = bcast_f(ga0[rr], k);   // (A@h0new)  -> gcWi1
          float b1 = bcast_f(hl0[rr], k);   // h0new      -> liWi1
          float b2 = bcast_f(ga1[rr], k);   // (A@h1old)  -> gcWh1
          float b3 = bcast_f(hl1[rr], k);   // h1old      -> liWh1
          acc1[rr].x += b0 * w0.x + b1 * w1.x + b2 * w2.x + b3 * w3.x;
          acc1[rr].y += b0 * w0.y + b1 * w1.y + b2 * w2.y + b3 * w3.y;
          acc1[rr].z += b0 * w0.z + b1 * w1.z + b2 * w2.z + b3 * w3.z;
          acc1[rr].w += b0 * w0.w + b1 * w1.w + b2 * w2.w + b3 * w3.w;
        }
      }
      if (ch + 1 < 16) {
        cur ^= 1;
        wbuf4[(cur << 9) + tid] = st;
        __syncthreads();
      }
    }

    // cell1 reduce + epilogue (kh=1)
    if (kh == 0) {  // stash acc1 partials (xbuf free: last read after loop A)
      xbuf[(size_t)(pair * 2 + 0) * 64 + lane] = acc1[0];
      xbuf[(size_t)(pair * 2 + 1) * 64 + lane] = acc1[1];
    }
    __syncthreads();
    if (kh == 1) {
#pragma unroll
      for (int rr = 0; rr < 2; rr++) {
        float4 o = xbuf[(size_t)(pair * 2 + rr) * 64 + lane];
        float gxv = acc1[rr].x + o.x, gyv = acc1[rr].y + o.y;
        float gzv = acc1[rr].z + o.z, gwv = acc1[rr].w + o.w;
        size_t gi = (size_t)(r0 + rr) * HH + lane;
        float si = 1.0f / (1.0f + __expf(-gxv));
        float sf = 1.0f / (1.0f + __expf(-gyv));
        float so = 1.0f / (1.0f + __expf(-gzv));
        float cn = sf * cprevA[rr] + si * tanhf(gwv);
        float hn = so * tanhf(cn);
        c1[gi] = cn;
        Pw[gi * 2 + 1] = hn;
      }
    }
  }
}

// ---------------------------------------------------------------------------
// Output projection: out[r,p] = h1[r,:] @ outW[:,p] + outb[p].
// h1 final = P0[..][1] (launch 48 writes P[0].y).
// ---------------------------------------------------------------------------
__launch_bounds__(256)
__global__ void k_out(const float* __restrict__ P0, const float* __restrict__ outW,
                      const float* __restrict__ outb, float* __restrict__ out) {
  int idx = blockIdx.x * 256 + threadIdx.x;
  if (idx >= NN * PP) return;
  int r = idx / PP, p = idx - r * PP;
  float acc = outb[p];
  const float* hrow = P0 + (size_t)r * 128;
#pragma unroll 16
  for (int k = 0; k < HH; k++) acc += hrow[k * 2 + 1] * outW[k * PP + p];
  out[idx] = acc;
}

extern "C" void kernel_launch(void* const* d_in, const int* in_sizes, int n_in,
                              void* d_out, int out_size, void* d_ws, size_t ws_size,
                              hipStream_t stream) {
  const float* x     = (const float*)d_in[0];
  const float* adj   = (const float*)d_in[1];
  const float* gcWi0 = (const float*)d_in[2];
  const float* gcbi0 = (const float*)d_in[3];
  const float* gcWh0 = (const float*)d_in[4];
  const float* gcbh0 = (const float*)d_in[5];
  const float* liWi0 = (const float*)d_in[6];
  const float* libi0 = (const float*)d_in[7];
  const float* liWh0 = (const float*)d_in[8];
  const float* libh0 = (const float*)d_in[9];
  const float* gcWi1 = (const float*)d_in[10];
  const float* gcbi1 = (const float*)d_in[11];
  const float* gcWh1 = (const float*)d_in[12];
  const float* gcbh1 = (const float*)d_in[13];
  const float* liWi1 = (const float*)d_in[14];
  const float* libi1 = (const float*)d_in[15];
  const float* liWh1 = (const float*)d_in[16];
  const float* libh1 = (const float*)d_in[17];
  const float* outW  = (const float*)d_in[18];
  const float* outb  = (const float*)d_in[19];

  char* ws = (char*)d_ws;
  size_t off = 0;
  auto carve = [&](size_t bytes) {
    void* p = ws + off;
    off += (bytes + 255) & ~(size_t)255;
    return p;
  };
  float*  dinv    = (float*)carve((size_t)NN * 4);
  int*    ell_col = (int*)carve((size_t)NN * CAP * 4);
  float*  ell_val = (float*)carve((size_t)NN * CAP * 4);
  int*    ell_cnt = (int*)carve((size_t)NN * 4);
  float*  state   = (float*)carve((size_t)6 * NH * 4);  // P0,P1 (2NH each), c0, c1
  float*  gax     = (float*)carve((size_t)TT * NN * 2 * 4);
  uint2*  Wgm     = (uint2*)carve((size_t)(8192 + 16384) * 8);  // bf16 quads, Wg0|Wg1
  float4* biasg0  = (float4*)carve((size_t)64 * 16);
  float4* biasg1  = (float4*)carve((size_t)64 * 16);
  float4* xq0     = (float4*)carve((size_t)256 * 16);

  uint2* Wg0 = Wgm;
  uint2* Wg1 = Wgm + 8192;
  float* P[2] = {state, state + 2 * NH};
  float* c0 = state + 4 * NH;
  float* c1 = state + 5 * NH;

  k_prep<<<512, 256, 0, stream>>>(gcbi0, gcbh0, libi0, libh0,
                                  gcbi1, gcbh1, libi1, libh1,
                                  gcWh0, liWh0, gcWi1, liWi1, gcWh1, liWh1,
                                  gcWi0, liWi0,
                                  state, Wg0, Wg1, biasg0, biasg1, xq0);
  k_build<<<NN, 256, 0, stream>>>(adj, dinv, ell_col, ell_val, ell_cnt);
  k_scale<<<(NN * CAP) / 256, 256, 0, stream>>>(dinv, ell_col, ell_val);
  k_gax<<<TT * 8, 256, 0, stream>>>(x, ell_col, ell_val, ell_cnt, gax);

  // Merged k-split step loop: launch k runs {cell0(k) + cell1(k-1)} per
  // 8-row 512-thread block. Launch k reads P[(k&1)^1], writes P[k&1].
  for (int k = 0; k <= TT; k++) {
    int A = k & 1;
    int c0on = (k < TT) ? 1 : 0;
    int c1on = (k > 0) ? 1 : 0;
    int tx = (k < TT) ? k : (TT - 1);              // xt/gaxt unused when k==TT
    k_cells<<<NN / 8, 512, 0, stream>>>(
        c0on, c1on, ell_col, ell_val, ell_cnt,
        (const float2*)P[A ^ 1], P[A], c0, c1,
        x + (size_t)tx * NN * 2, gax + (size_t)tx * NN * 2,
        Wgm, biasg0, xq0, biasg1);
  }

  // Launch 48 (A=0) wrote h1(47) into P[0].y
  k_out<<<(NN * PP + 255) / 256, 256, 0, stream>>>(P[0], outW, outb, (float*)d_out);
}

// Round 16
// 1733.823 us; speedup vs baseline: 1.0525x; 1.0525x over previous
//
#include <hip/hip_runtime.h>
#include <math.h>

// Problem constants
#define NN 4096
#define TT 48
#define HH 64
#define GG 256   // 4*H
#define PP 12
#define CAP 192  // ELL slots per row, 3 x 64 -> whole-wave chunk loads, no guard
#define NH (NN * HH)

// readlane broadcast: uniform lane index -> SGPR broadcast, off the LDS pipe
__device__ __forceinline__ float bcast_f(float v, int lane) {
  return __int_as_float(__builtin_amdgcn_readlane(__float_as_int(v), lane));
}
__device__ __forceinline__ int bcast_i(int v, int lane) {
  return __builtin_amdgcn_readlane(v, lane);
}

// ---------------------------------------------------------------------------
// h-state: paired buffers P[2], each [N][64][2]: {h0, h1} interleaved.
// Launch k (k=0..48) computes cell0(t=k) [k<48] and cell1(s=k-1) [k>0]:
//   READS only P[(k&1)^1], WRITES only P[k&1] (disjoint float2 slots).
// Final h1(47) in P[0].y.
//
// R15 = R12 RESTORED (verified 1736us) -- FINAL. R14 (bf16-packed weights)
// passed correctness (absmax 9.8e-4 < 3e-3) but regressed to 1825us:
// halving LDS bytes didn't shorten the step (ds_read COUNT unchanged) and
// the unpack VALU (~768 ops/wave) outweighed the byte savings. Combined
// with R8 (barriers null) and R9/R10 (TLP the only mover), the step is
// dependency/latency-bound at 16 waves/CU with all pipes <60%; exhausted
// levers: occupancy (R1/R10), traffic (R2-R6/R14), dedup (R7), chunk size
// (R8), rows/wave (R9), persistent-cooperative (R11: not graph-capturable
// + cross-XCD L2 non-coherence), tail guards (R12 neutral).
//
// R10/R12 design (verified): MERGED + K-SPLIT + INTERLEAVED WEIGHT LAYOUT.
// 512-thr blocks (4 pairs x 2 k-half waves), 8 rows/block, grid 512 ->
// 4096 waves = 16/CU. Wave gathers ONE row (pair exchanges ga via LDS ->
// gather 1x, spread over 2x waves); dense loops: wave computes its k-half
// for the pair's 2 rows. Wg k-dim PERMUTED in k_prep so each 16 KB chunk
// holds k's of BOTH halves -> both kh waves compute on every chunk.
// Partial-acc reduction via the 8 KB exchange buffer; kh=0 finalizes
// cell0, kh=1 cell1. __launch_bounds__(512,4) -> VGPR<=128.
// ch-loops #pragma unroll 1 (R4/R5: full unroll hoists prefetch -> VGPR
// 256 + scratch spills).
// History: R0 48.5 -> R6 42.4 (unroll-1 ping-pong staging) -> R7 40.0
// (merged roles, gather once) -> R8 ~40 (chunk size moot) -> R9 48
// (1 wave/SIMD fails) -> R10 ~33us/launch, 1727us total -> R11 FAILED ->
// R12 1736 (consolidated) -> R14 bf16 1825 (regression, reverted).
//
// GATE-QUAD mapping: lane j owns cols {j, j+64, j+128, j+192} = (i,f,o,g)
// of hidden unit j. PERMUTED slot order (chunk-interleaved k-halves):
//   Wg0: slot0(k) = (k%32/4)*8 + (k/32)*4 + (k%4);  f4 = slot*128 + m*64 + j
//        m in {gcWh0, liWh0}; chunk c (8 slots) holds k {4c..4c+3, 32+4c..}
//   Wg1: slot1(k) = (k%32/2)*4 + (k/32)*2 + (k%2);  f4 = 8192 + slot*256
//        + m*64 + j; m in {gcWi1, liWi1, gcWh1, liWh1}; chunk c (4 slots)
//        holds k {2c, 2c+1, 32+2c, 32+2c+1}
// ---------------------------------------------------------------------------
__launch_bounds__(256)
__global__ void k_prep(const float* gcbi0, const float* gcbh0,
                       const float* libi0, const float* libh0,
                       const float* gcbi1, const float* gcbh1,
                       const float* libi1, const float* libh1,
                       const float* gcWh0, const float* liWh0,
                       const float* gcWi1, const float* liWi1,
                       const float* gcWh1, const float* liWh1,
                       const float* gcWi0, const float* liWi0,
                       float* state, float4* Wg0, float4* Wg1,
                       float4* biasg0, float4* biasg1, float4* xq0) {
  int idx = blockIdx.x * 256 + threadIdx.x;
  int stride = gridDim.x * 256;
  for (int i = idx; i < 6 * NH; i += stride) state[i] = 0.0f;  // P0,P1,c0,c1
  for (int i = idx; i < 64 * 2 * 64; i += stride) {
    int j = i & 63, m = (i >> 6) & 1, k = i >> 7;
    const float* W = m ? liWh0 : gcWh0;
    int slot = ((k & 31) >> 2) * 8 + (k >> 5) * 4 + (k & 3);
    Wg0[slot * 128 + m * 64 + j] =
        make_float4(W[k * GG + j], W[k * GG + j + 64],
                    W[k * GG + j + 128], W[k * GG + j + 192]);
  }
  for (int i = idx; i < 64 * 4 * 64; i += stride) {
    int j = i & 63, m = (i >> 6) & 3, k = i >> 8;
    const float* W = (m == 0) ? gcWi1 : (m == 1) ? liWi1 : (m == 2) ? gcWh1 : liWh1;
    int slot = ((k & 31) >> 1) * 4 + (k >> 5) * 2 + (k & 1);
    Wg1[slot * 256 + m * 64 + j] =
        make_float4(W[k * GG + j], W[k * GG + j + 64],
                    W[k * GG + j + 128], W[k * GG + j + 192]);
  }
  if (idx < 64) {
    int j = idx;
    biasg0[j] = make_float4(
        gcbi0[j] + gcbh0[j] + libi0[j] + libh0[j],
        gcbi0[j + 64] + gcbh0[j + 64] + libi0[j + 64] + libh0[j + 64],
        gcbi0[j + 128] + gcbh0[j + 128] + libi0[j + 128] + libh0[j + 128],
        gcbi0[j + 192] + gcbh0[j + 192] + libi0[j + 192] + libh0[j + 192]);
    biasg1[j] = make_float4(
        gcbi1[j] + gcbh1[j] + libi1[j] + libh1[j],
        gcbi1[j + 64] + gcbh1[j + 64] + libi1[j + 64] + libh1[j + 64],
        gcbi1[j + 128] + gcbh1[j + 128] + libi1[j + 128] + libh1[j + 128],
        gcbi1[j + 192] + gcbh1[j + 192] + libi1[j + 192] + libh1[j + 192]);
  } else if (idx < 320) {
    int i = idx - 64;           // i = m*64 + j
    int j = i & 63, m = i >> 6; // m: 0,1 -> gcWi0 row 0/1; 2,3 -> liWi0 row 0/1
    const float* W = (m < 2) ? gcWi0 : liWi0;
    int kk = m & 1;
    xq0[i] = make_float4(W[kk * GG + j], W[kk * GG + j + 64],
                         W[kk * GG + j + 128], W[kk * GG + j + 192]);
  }
}

// ---------------------------------------------------------------------------
// Single adj pass: raw ELL (incl. +I diag) + dinv. Zero-fills ALL CAP slots
// (re-poison semantics: padding must be (col=0, val=0)). cnt padded to x8.
// ---------------------------------------------------------------------------
__launch_bounds__(256)
__global__ void k_build(const float* adj, float* dinv,
                        int* ell_col, float* ell_val, int* ell_cnt) {
  int r = blockIdx.x;
  __shared__ int cnt;
  __shared__ float red[256];
  if (threadIdx.x == 0) cnt = 0;
  __syncthreads();
  const float* row = adj + (size_t)r * NN;
  float s = 0.0f;
  for (int c = threadIdx.x; c < NN; c += 256) {
    float a = row[c];
    if (c == r) a += 1.0f;   // A = adj + I
    s += a;
    if (a != 0.0f) {
      int pos = atomicAdd(&cnt, 1);
      if (pos < CAP) {
        ell_col[(size_t)r * CAP + pos] = c;
        ell_val[(size_t)r * CAP + pos] = a;
      }
    }
  }
  red[threadIdx.x] = s;
  __syncthreads();
  for (int st = 128; st > 0; st >>= 1) {
    if (threadIdx.x < st) red[threadIdx.x] += red[threadIdx.x + st];
    __syncthreads();
  }
  int n = cnt < CAP ? cnt : CAP;
  for (int j = n + (int)threadIdx.x; j < CAP; j += 256) {
    ell_col[(size_t)r * CAP + j] = 0;
    ell_val[(size_t)r * CAP + j] = 0.0f;
  }
  if (threadIdx.x == 0) {
    int npad = (n + 7) & ~7;
    if (npad > CAP) npad = CAP;
    ell_cnt[r] = npad;
    dinv[r] = 1.0f / sqrtf(red[0]);  // rowsum + 1 >= 1
  }
}

__launch_bounds__(256)
__global__ void k_scale(const float* dinv, const int* ell_col, float* ell_val) {
  int idx = blockIdx.x * 256 + threadIdx.x;  // over NN*CAP
  int r = idx / CAP;
  if (r >= NN) return;
  float v = ell_val[idx];
  if (v != 0.0f) ell_val[idx] = v * dinv[r] * dinv[ell_col[idx]];
}

// ---------------------------------------------------------------------------
// Precompute gax[t][r][c] = (A @ x_t)[r][c]. Block = (t, 512-row segment).
// ---------------------------------------------------------------------------
__launch_bounds__(256)
__global__ void k_gax(const float* x, const int* ell_col, const float* ell_val,
                      const int* ell_cnt, float* gax) {
  int t = blockIdx.x >> 3;
  int seg = blockIdx.x & 7;
  __shared__ float xs[NN * 2];
  const float* xt = x + (size_t)t * NN * 2;
  for (int i = threadIdx.x; i < NN * 2; i += 256) xs[i] = xt[i];
  __syncthreads();
  int base = seg * 512 * 2;
  for (int oo = threadIdx.x; oo < 512 * 2; oo += 256) {
    int o = base + oo;
    int r = o >> 1, cmp = o & 1;
    int cnt = ell_cnt[r];
    const int* cp = ell_col + (size_t)r * CAP;
    const float* vp = ell_val + (size_t)r * CAP;
    float acc = 0.0f;
    for (int j = 0; j < cnt; j += 4) {
      acc += vp[j]     * xs[cp[j]     * 2 + cmp];
      acc += vp[j + 1] * xs[cp[j + 1] * 2 + cmp];
      acc += vp[j + 2] * xs[cp[j + 2] * 2 + cmp];
      acc += vp[j + 3] * xs[cp[j + 3] * 2 + cmp];
    }
    gax[(size_t)t * NN * 2 + o] = acc;
  }
}

// ---------------------------------------------------------------------------
// Merged k-split step kernel: 512 threads = 8 waves = 4 pairs x 2 k-halves.
// 8 rows/block (2 per pair). Wave (pair,kh) gathers row r0+kh; pair
// exchanges ga via xbuf; both dense loops computed per k-half on every
// chunk (interleaved layout). kh=0 finalizes cell0, kh=1 cell1.
// Tail guards: loop A runs only if c0on; loop B only if c1on (uniform).
// LDS: 2 x 16 KB ping-pong + 8 KB exchange/reduction = 40 KB -> 2 blk/CU.
// ---------------------------------------------------------------------------
__launch_bounds__(512, 4)
__global__ void k_cells(int c0on, int c1on,
                        const int* __restrict__ ell_col,
                        const float* __restrict__ ell_val,
                        const int* __restrict__ ell_cnt,
                        const float2* __restrict__ Pr, float* __restrict__ Pw,
                        float* __restrict__ c0, float* __restrict__ c1,
                        const float* __restrict__ xt, const float* __restrict__ gaxt,
                        const float4* __restrict__ Wg,
                        const float4* __restrict__ biasg0,
                        const float4* __restrict__ xq0,
                        const float4* __restrict__ biasg1) {
  __shared__ float4 wbuf[2048];  // 2 x 16 KB ping-pong
  __shared__ float4 xbuf[512];   // 8 KB: ga-exchange (early), acc-reduce (late)
  const int tid = threadIdx.x;
  const int wave = tid >> 6, lane = tid & 63;
  const int pair = wave >> 1, kh = wave & 1;
  const int r0 = blockIdx.x * 8 + pair * 2;
  const int myrow = r0 + kh;

  // chunk-0 prefetch (2 f4/thread): completes under the gather phase.
  // When loop A is disabled (k==TT launch), chain starts at Wg1.
  const float4* pf = (c0on ? Wg : (Wg + 8192)) + tid;
  float4 st0 = pf[0], st1 = pf[512];
  pf += 1024;

  // c-state loads for the role this wave finalizes (kh=0: cell0, kh=1: cell1)
  float cprevA[2];
#pragma unroll
  for (int rr = 0; rr < 2; rr++) {
    size_t gi = (size_t)(r0 + rr) * HH + lane;
    cprevA[rr] = (kh == 0) ? c0[gi] : c1[gi];
  }

  // gather OWN row (both float2 components)
  int cnt = ell_cnt[myrow];
  int myc[3]; float myv[3];
#pragma unroll
  for (int chk = 0; chk < 3; chk++) {
    myc[chk] = ell_col[(size_t)myrow * CAP + chk * 64 + lane];
    myv[chk] = ell_val[(size_t)myrow * CAP + chk * 64 + lane];
  }
  float a0 = 0.0f, a1 = 0.0f;
#pragma unroll
  for (int chk = 0; chk < 3; chk++) {
    int base = chk * 64;
    if (base < cnt) {
      int lim = cnt - base; if (lim > 64) lim = 64;  // multiple of 8
      int mc = myc[chk]; float mv = myv[chk];
      for (int m = 0; m < lim; m += 8) {
        float2 ld[8]; float vv[8];
#pragma unroll
        for (int i = 0; i < 8; i++) {
          int cc = bcast_i(mc, m + i);
          vv[i] = bcast_f(mv, m + i);
          ld[i] = Pr[(size_t)cc * 64 + lane];
        }
#pragma unroll
        for (int i = 0; i < 8; i++) {
          a0 += vv[i] * ld[i].x;
          a1 += vv[i] * ld[i].y;
        }
      }
    }
  }
  // publish ga for my row; load hl for both rows directly
  {
    float2* gx = (float2*)xbuf;
    gx[(size_t)(pair * 2 + kh) * 64 + lane] = make_float2(a0, a1);
  }
  float hl0[2], hl1[2];
#pragma unroll
  for (int rr = 0; rr < 2; rr++) {
    float2 hh = Pr[(size_t)(r0 + rr) * 64 + lane];
    hl0[rr] = hh.x;  // h0(k-1): cell0 liWh0 + cell1 liWi1
    hl1[rr] = hh.y;  // h1(k-2): cell1 liWh1
  }

  // accumulator inits: bias/x terms live in exactly one k-half
  float4 acc0[2], acc1[2];
  if (kh == 0) {
    float4 b = biasg0[lane];
    float4 qg0 = xq0[lane], qg1 = xq0[64 + lane];
    float4 ql0 = xq0[128 + lane], ql1 = xq0[192 + lane];
#pragma unroll
    for (int rr = 0; rr < 2; rr++) {
      float xx0 = xt[(size_t)(r0 + rr) * 2];
      float xx1 = xt[(size_t)(r0 + rr) * 2 + 1];
      float gg0 = gaxt[(size_t)(r0 + rr) * 2];
      float gg1 = gaxt[(size_t)(r0 + rr) * 2 + 1];
      acc0[rr].x = b.x + gg0 * qg0.x + gg1 * qg1.x + xx0 * ql0.x + xx1 * ql1.x;
      acc0[rr].y = b.y + gg0 * qg0.y + gg1 * qg1.y + xx0 * ql0.y + xx1 * ql1.y;
      acc0[rr].z = b.z + gg0 * qg0.z + gg1 * qg1.z + xx0 * ql0.z + xx1 * ql1.z;
      acc0[rr].w = b.w + gg0 * qg0.w + gg1 * qg1.w + xx0 * ql0.w + xx1 * ql1.w;
    }
    acc1[0] = make_float4(0.f, 0.f, 0.f, 0.f);
    acc1[1] = make_float4(0.f, 0.f, 0.f, 0.f);
  } else {
    acc0[0] = make_float4(0.f, 0.f, 0.f, 0.f);
    acc0[1] = make_float4(0.f, 0.f, 0.f, 0.f);
    float4 b1 = biasg1[lane];
    acc1[0] = b1; acc1[1] = b1;
  }

  // stage chunk 0; barrier makes gx + chunk0 visible
  wbuf[tid] = st0; wbuf[512 + tid] = st1;
  __syncthreads();

  // read pair's ga for both rows
  float ga0[2], ga1[2];
  {
    const float2* gx = (const float2*)xbuf;
#pragma unroll
    for (int rr = 0; rr < 2; rr++) {
      float2 g = gx[(size_t)(pair * 2 + rr) * 64 + lane];
      ga0[rr] = g.x;  // A@h0(k-1): cell0 gcWh0 + cell1 gcWi1
      ga1[rr] = g.y;  // A@h1(k-2): cell1 gcWh1
    }
  }

  int cur = 0;
  if (c0on) {
    // loop A: Wg0, 8 chunks; each wave computes its 4 k's per chunk.
    // ALWAYS prefetch next (ch=7 pulls Wg1 chunk 0 across the boundary).
#pragma unroll 1
    for (int ch = 0; ch < 8; ch++) {
      st0 = pf[0]; st1 = pf[512];
      pf += 1024;
      const float4* wb = wbuf + (cur << 10);
      const int kb = kh * 32 + ch * 4;
      const int wbase = kh * 4;
#pragma unroll
      for (int q = 0; q < 4; q++) {
        int k = kb + q;
        float4 w0 = wb[(wbase + q) * 128 + lane];
        float4 w1 = wb[(wbase + q) * 128 + 64 + lane];
#pragma unroll
        for (int rr = 0; rr < 2; rr++) {
          float b0 = bcast_f(ga0[rr], k);
          float b1 = bcast_f(hl0[rr], k);
          acc0[rr].x += b0 * w0.x + b1 * w1.x;
          acc0[rr].y += b0 * w0.y + b1 * w1.y;
          acc0[rr].z += b0 * w0.z + b1 * w1.z;
          acc0[rr].w += b0 * w0.w + b1 * w1.w;
        }
      }
      cur ^= 1;
      float4* dst = wbuf + (cur << 10) + tid;
      dst[0] = st0; dst[512] = st1;
      if (ch == 7 && kh == 1) {  // stash acc0 partials before the barrier
        xbuf[(size_t)(pair * 2 + 0) * 64 + lane] = acc0[0];
        xbuf[(size_t)(pair * 2 + 1) * 64 + lane] = acc0[1];
      }
      __syncthreads();  // writes + stash visible; all waves past chunk ch
    }

    // cell0 reduce + epilogue (kh=0); overlaps kh=1's loop-B start
    if (kh == 0) {
#pragma unroll
      for (int rr = 0; rr < 2; rr++) {
        float4 o = xbuf[(size_t)(pair * 2 + rr) * 64 + lane];
        float gxv = acc0[rr].x + o.x, gyv = acc0[rr].y + o.y;
        float gzv = acc0[rr].z + o.z, gwv = acc0[rr].w + o.w;
        size_t gi = (size_t)(r0 + rr) * HH + lane;
        float si = 1.0f / (1.0f + __expf(-gxv));
        float sf = 1.0f / (1.0f + __expf(-gyv));
        float so = 1.0f / (1.0f + __expf(-gzv));
        float cn = sf * cprevA[rr] + si * tanhf(gwv);
        float hn = so * tanhf(cn);
        c0[gi] = cn;
        Pw[gi * 2 + 0] = hn;
      }
    }
  }

  if (c1on) {
    // loop B: Wg1, 16 chunks; each wave computes its 2 k's per chunk.
    // buf[cur] holds Wg1 chunk 0 (staged at ch=7 above, or at entry when
    // loop A was skipped).
#pragma unroll 1
    for (int ch = 0; ch < 16; ch++) {
      if (ch + 1 < 16) {
        st0 = pf[0]; st1 = pf[512];
        pf += 1024;
      }
      const float4* wb = wbuf + (cur << 10);
      const int kb = kh * 32 + ch * 2;
      const int wbase = kh * 2;
#pragma unroll
      for (int q = 0; q < 2; q++) {
        int k = kb + q;
        const float4* wp = wb + (wbase + q) * 256 + lane;
        float4 w0 = wp[0], w1 = wp[64], w2 = wp[128], w3 = wp[192];
#pragma unroll
        for (int rr = 0; rr < 2; rr++) {
          float b0 = bcast_f(ga0[rr], k);   // (A@h0new)  -> gcWi1
          float b1 = bcast_f(hl0[rr], k);   // h0new      -> liWi1
          float b2 = bcast_f(ga1[rr], k);   // (A@h1old)  -> gcWh1
          float b3 = bcast_f(hl1[rr], k);   // h1old      -> liWh1
          acc1[rr].x += b0 * w0.x + b1 * w1.x + b2 * w2.x + b3 * w3.x;
          acc1[rr].y += b0 * w0.y + b1 * w1.y + b2 * w2.y + b3 * w3.y;
          acc1[rr].z += b0 * w0.z + b1 * w1.z + b2 * w2.z + b3 * w3.z;
          acc1[rr].w += b0 * w0.w + b1 * w1.w + b2 * w2.w + b3 * w3.w;
        }
      }
      if (ch + 1 < 16) {
        cur ^= 1;
        float4* dst = wbuf + (cur << 10) + tid;
        dst[0] = st0; dst[512] = st1;
        __syncthreads();
      }
    }

    // cell1 reduce + epilogue (kh=1)
    if (kh == 0) {  // stash acc1 partials (xbuf free: last read after loop A)
      xbuf[(size_t)(pair * 2 + 0) * 64 + lane] = acc1[0];
      xbuf[(size_t)(pair * 2 + 1) * 64 + lane] = acc1[1];
    }
    __syncthreads();
    if (kh == 1) {
#pragma unroll
      for (int rr = 0; rr < 2; rr++) {
        float4 o = xbuf[(size_t)(pair * 2 + rr) * 64 + lane];
        float gxv = acc1[rr].x + o.x, gyv = acc1[rr].y + o.y;
        float gzv = acc1[rr].z + o.z, gwv = acc1[rr].w + o.w;
        size_t gi = (size_t)(r0 + rr) * HH + lane;
        float si = 1.0f / (1.0f + __expf(-gxv));
        float sf = 1.0f / (1.0f + __expf(-gyv));
        float so = 1.0f / (1.0f + __expf(-gzv));
        float cn = sf * cprevA[rr] + si * tanhf(gwv);
        float hn = so * tanhf(cn);
        c1[gi] = cn;
        Pw[gi * 2 + 1] = hn;
      }
    }
  }
}

// ---------------------------------------------------------------------------
// Output projection: out[r,p] = h1[r,:] @ outW[:,p] + outb[p].
// h1 final = P0[..][1] (launch 48 writes P[0].y).
// ---------------------------------------------------------------------------
__launch_bounds__(256)
__global__ void k_out(const float* __restrict__ P0, const float* __restrict__ outW,
                      const float* __restrict__ outb, float* __restrict__ out) {
  int idx = blockIdx.x * 256 + threadIdx.x;
  if (idx >= NN * PP) return;
  int r = idx / PP, p = idx - r * PP;
  float acc = outb[p];
  const float* hrow = P0 + (size_t)r * 128;
#pragma unroll 16
  for (int k = 0; k < HH; k++) acc += hrow[k * 2 + 1] * outW[k * PP + p];
  out[idx] = acc;
}

extern "C" void kernel_launch(void* const* d_in, const int* in_sizes, int n_in,
                              void* d_out, int out_size, void* d_ws, size_t ws_size,
                              hipStream_t stream) {
  const float* x     = (const float*)d_in[0];
  const float* adj   = (const float*)d_in[1];
  const float* gcWi0 = (const float*)d_in[2];
  const float* gcbi0 = (const float*)d_in[3];
  const float* gcWh0 = (const float*)d_in[4];
  const float* gcbh0 = (const float*)d_in[5];
  const float* liWi0 = (const float*)d_in[6];
  const float* libi0 = (const float*)d_in[7];
  const float* liWh0 = (const float*)d_in[8];
  const float* libh0 = (const float*)d_in[9];
  const float* gcWi1 = (const float*)d_in[10];
  const float* gcbi1 = (const float*)d_in[11];
  const float* gcWh1 = (const float*)d_in[12];
  const float* gcbh1 = (const float*)d_in[13];
  const float* liWi1 = (const float*)d_in[14];
  const float* libi1 = (const float*)d_in[15];
  const float* liWh1 = (const float*)d_in[16];
  const float* libh1 = (const float*)d_in[17];
  const float* outW  = (const float*)d_in[18];
  const float* outb  = (const float*)d_in[19];

  char* ws = (char*)d_ws;
  size_t off = 0;
  auto carve = [&](size_t bytes) {
    void* p = ws + off;
    off += (bytes + 255) & ~(size_t)255;
    return p;
  };
  float*  dinv    = (float*)carve((size_t)NN * 4);
  int*    ell_col = (int*)carve((size_t)NN * CAP * 4);
  float*  ell_val = (float*)carve((size_t)NN * CAP * 4);
  int*    ell_cnt = (int*)carve((size_t)NN * 4);
  float*  state   = (float*)carve((size_t)6 * NH * 4);  // P0,P1 (2NH each), c0, c1
  float*  gax     = (float*)carve((size_t)TT * NN * 2 * 4);
  float4* Wgm     = (float4*)carve((size_t)(8192 + 16384) * 16);  // Wg0|Wg1 contiguous
  float4* biasg0  = (float4*)carve((size_t)64 * 16);
  float4* biasg1  = (float4*)carve((size_t)64 * 16);
  float4* xq0     = (float4*)carve((size_t)256 * 16);

  float4* Wg0 = Wgm;
  float4* Wg1 = Wgm + 8192;
  float* P[2] = {state, state + 2 * NH};
  float* c0 = state + 4 * NH;
  float* c1 = state + 5 * NH;

  k_prep<<<512, 256, 0, stream>>>(gcbi0, gcbh0, libi0, libh0,
                                  gcbi1, gcbh1, libi1, libh1,
                                  gcWh0, liWh0, gcWi1, liWi1, gcWh1, liWh1,
                                  gcWi0, liWi0,
                                  state, Wg0, Wg1, biasg0, biasg1, xq0);
  k_build<<<NN, 256, 0, stream>>>(adj, dinv, ell_col, ell_val, ell_cnt);
  k_scale<<<(NN * CAP) / 256, 256, 0, stream>>>(dinv, ell_col, ell_val);
  k_gax<<<TT * 8, 256, 0, stream>>>(x, ell_col, ell_val, ell_cnt, gax);

  // Merged k-split step loop: launch k runs {cell0(k) + cell1(k-1)} per
  // 8-row 512-thread block. Launch k reads P[(k&1)^1], writes P[k&1].
  for (int k = 0; k <= TT; k++) {
    int A = k & 1;
    int c0on = (k < TT) ? 1 : 0;
    int c1on = (k > 0) ? 1 : 0;
    int tx = (k < TT) ? k : (TT - 1);              // xt/gaxt unused when k==TT
    k_cells<<<NN / 8, 512, 0, stream>>>(
        c0on, c1on, ell_col, ell_val, ell_cnt,
        (const float2*)P[A ^ 1], P[A], c0, c1,
        x + (size_t)tx * NN * 2, gax + (size_t)tx * NN * 2,
        Wgm, biasg0, xq0, biasg1);
  }

  // Launch 48 (A=0) wrote h1(47) into P[0].y
  k_out<<<(NN * PP + 255) / 256, 256, 0, stream>>>(P[0], outW, outb, (float*)d_out);
}